// Round 3
// baseline (1073.258 us; speedup 1.0000x reference)
//
#include <hip/hip_runtime.h>
#include <cmath>

// Problem constants
#define NROWS 16384
#define DDIM  512

__device__ __forceinline__ float gelu_tanh(float x) {
  float x3 = x * x * x;
  float t = tanhf(0.79788456080286535588f * (x + 0.044715f * x3));
  return 0.5f * x * (1.0f + t);
}

__device__ __forceinline__ void ld8(const float* p, float* v) {
  float4 a = *(const float4*)p;
  float4 b = *(const float4*)(p + 256);
  v[0] = a.x; v[1] = a.y; v[2] = a.z; v[3] = a.w;
  v[4] = b.x; v[5] = b.y; v[6] = b.z; v[7] = b.w;
}

__device__ __forceinline__ void st8(float* p, const float* v) {
  float4 a = make_float4(v[0], v[1], v[2], v[3]);
  float4 b = make_float4(v[4], v[5], v[6], v[7]);
  *(float4*)p = a;
  *(float4*)(p + 256) = b;
}

__device__ __forceinline__ float wave_sum(float v) {
#pragma unroll
  for (int m = 1; m < 64; m <<= 1) v += __shfl_xor(v, m, 64);
  return v;
}

__device__ __forceinline__ double wave_sum_d(double v) {
#pragma unroll
  for (int m = 1; m < 64; m <<= 1) v += __shfl_xor(v, m, 64);
  return v;
}

// ---------------------------------------------------------------------------
// Kernel 1: per-row prep.
// Gate path: o (pre-sigmoid logit) in FP64 for true ordering, then the
// sigmoid is evaluated emulating a float32 numpy chain with correct rounding
// per step: o32=(f32)o, e32=f32(exp(-o32)), a32=1+e32, w32=1/a32.
// Weight gaps (~1e-4) sit near fp32 resolution at 0.5 (6e-8), so the
// reference's fp32 weights genuinely COLLIDE in tens of rows and stable
// argsort falls back to index order — we must collide at the same places.
//   - x[b,:] = sum_k conv_w[rank(k)]*w32[k]*text[b,k,:] + conv_b
//   - column sum / sumsq stats of x and of image (for BatchNorm)
// Grid: 512 blocks x 256 threads; each wave (4/block) handles 8 rows.
// ---------------------------------------------------------------------------
__global__ __launch_bounds__(256) void prep_kernel(
    const float* __restrict__ img, const float* __restrict__ txt,
    const float* __restrict__ wg_w1, const float* __restrict__ wg_b1,
    const float* __restrict__ wg_w2, const float* __restrict__ wg_b2,
    const float* __restrict__ conv_w, const float* __restrict__ conv_b,
    float* __restrict__ x,
    float* __restrict__ accXs, float* __restrict__ accXq,
    float* __restrict__ accIs, float* __restrict__ accIq) {
  __shared__ float csX[512], cqX[512], csI[512], cqI[512];
  const int tid = threadIdx.x;
  for (int i = tid; i < 512; i += 256) {
    csX[i] = 0.f; cqX[i] = 0.f; csI[i] = 0.f; cqI[i] = 0.f;
  }
  __syncthreads();

  const int lane = tid & 63;
  const int gwave = blockIdx.x * 4 + (tid >> 6);  // 0..2047

  const float cb = conv_b[0];
  const double b2 = (double)wg_b2[0];
  double w1r[16], b1r[16], w2r[16];
#pragma unroll
  for (int i = 0; i < 16; i++) {
    w1r[i] = (double)wg_w1[i]; b1r[i] = (double)wg_b1[i]; w2r[i] = (double)wg_w2[i];
  }
  float cw[5];
#pragma unroll
  for (int k = 0; k < 5; k++) cw[k] = conv_w[k];

  float sX[8] = {0, 0, 0, 0, 0, 0, 0, 0}, qX[8] = {0, 0, 0, 0, 0, 0, 0, 0};
  float sI[8] = {0, 0, 0, 0, 0, 0, 0, 0}, qI[8] = {0, 0, 0, 0, 0, 0, 0, 0};

  for (int it = 0; it < 8; it++) {
    const int r = gwave * 8 + it;
    const float* ip = img + (size_t)r * DDIM + lane * 4;
    float iv[8];
    ld8(ip, iv);
    double ss = 0.0;
#pragma unroll
    for (int j = 0; j < 8; j++) ss += (double)iv[j] * (double)iv[j];
    ss = wave_sum_d(ss);
    const double dimg = fmax(sqrt(ss), 1e-12);

    float tv[5][8];
    double simv[5];
#pragma unroll
    for (int k = 0; k < 5; k++) {
      const float* tp = txt + ((size_t)r * 5 + k) * DDIM + lane * 4;
      ld8(tp, tv[k]);
      double s2 = 0.0, dp = 0.0;
#pragma unroll
      for (int j = 0; j < 8; j++) {
        s2 += (double)tv[k][j] * (double)tv[k][j];
        dp += (double)iv[j] * (double)tv[k][j];
      }
#pragma unroll
      for (int m = 1; m < 64; m <<= 1) {
        s2 += __shfl_xor(s2, m, 64);
        dp += __shfl_xor(dp, m, 64);
      }
      const double dt = fmax(sqrt(s2), 1e-12);
      simv[k] = dp / (dimg * dt);
    }

    // WeightGate logit in fp64 (true ordering), sigmoid emulating fp32 chain
    float wv[5];
#pragma unroll
    for (int k = 0; k < 5; k++) {
      double o = b2;
#pragma unroll
      for (int i = 0; i < 16; i++) {
        double h = simv[k] * w1r[i] + b1r[i];
        h = fmax(h, 0.0);
        o += h * w2r[i];
      }
      // fp32 sigmoid with per-step correct rounding: 1/(1+exp(-x)) in f32
      float o32 = (float)o;
      float e32 = (float)exp(-(double)o32);  // correctly-rounded f32 exp
      float a32 = 1.0f + e32;                // f32 add
      wv[k] = 1.0f / a32;                    // f32 div
    }

    // stable descending rank -> coefficient (matches argsort(-w) stable,
    // including fp32 weight collisions resolved by original index)
    float c[5];
#pragma unroll
    for (int k = 0; k < 5; k++) {
      int rk = 0;
#pragma unroll
      for (int j = 0; j < 5; j++)
        rk += (int)((wv[j] > wv[k]) || ((wv[j] == wv[k]) && (j < k)));
      c[k] = cw[rk] * wv[k];
    }

    float xv[8];
#pragma unroll
    for (int j = 0; j < 8; j++) {
      float v = cb;
#pragma unroll
      for (int k = 0; k < 5; k++) v = fmaf(c[k], tv[k][j], v);
      xv[j] = v;
    }
    st8(x + (size_t)r * DDIM + lane * 4, xv);

#pragma unroll
    for (int j = 0; j < 8; j++) {
      sX[j] += xv[j]; qX[j] += xv[j] * xv[j];
      sI[j] += iv[j]; qI[j] += iv[j] * iv[j];
    }
  }

  // merge per-thread stats into block LDS (columns: lane*4+j and 256+lane*4+j)
  const int c0 = lane * 4, c1 = 256 + lane * 4;
#pragma unroll
  for (int j = 0; j < 4; j++) {
    atomicAdd(&csX[c0 + j], sX[j]);     atomicAdd(&cqX[c0 + j], qX[j]);
    atomicAdd(&csX[c1 + j], sX[4 + j]); atomicAdd(&cqX[c1 + j], qX[4 + j]);
    atomicAdd(&csI[c0 + j], sI[j]);     atomicAdd(&cqI[c0 + j], qI[j]);
    atomicAdd(&csI[c1 + j], sI[4 + j]); atomicAdd(&cqI[c1 + j], qI[4 + j]);
  }
  __syncthreads();
  for (int i = tid; i < 512; i += 256) {
    atomicAdd(&accXs[i], csX[i]); atomicAdd(&accXq[i], cqX[i]);
    atomicAdd(&accIs[i], csI[i]); atomicAdd(&accIq[i], cqI[i]);
  }
}

// ---------------------------------------------------------------------------
// finalize: BN stats -> affine (scale = g*rstd, shift = b - mean*scale)
// ---------------------------------------------------------------------------
__global__ void finalize_kernel(const float* __restrict__ s, const float* __restrict__ q,
                                const float* __restrict__ g, const float* __restrict__ b,
                                float* __restrict__ scale, float* __restrict__ shift,
                                float invM) {
  int j = threadIdx.x;
  if (j >= 512) return;
  float m = s[j] * invM;
  float v = q[j] * invM - m * m;
  float r = 1.0f / sqrtf(v + 1e-5f);
  float sc = g[j] * r;
  scale[j] = sc;
  shift[j] = fmaf(-m, sc, b[j]);
}

// ---------------------------------------------------------------------------
// GEMM: C = act( (A*scale+shift) @ W + bias ), A:[16384,512], W:[512,512]
// BM=BN=64, BK=16, 256 threads, 4x4 micro-tile per thread.
// Optional column-stats epilogue (sum / sumsq of post-activation C).
// ---------------------------------------------------------------------------
__global__ __launch_bounds__(256) void gemm_kernel(
    const float* __restrict__ A, const float* __restrict__ W,
    const float* __restrict__ bias,
    const float* __restrict__ scale, const float* __restrict__ shift,
    float* __restrict__ C, int do_gelu,
    float* __restrict__ accS, float* __restrict__ accQ) {
  __shared__ float As[16][68];
  __shared__ float Bs[16][68];
  __shared__ float colS[64], colQ[64];
  const int tid = threadIdx.x;
  const int tx = tid & 15, ty = tid >> 4;
  const int bm = blockIdx.x * 64;
  const int bn = blockIdx.y * 64;
  float acc[4][4] = {};

  for (int k0 = 0; k0 < 512; k0 += 16) {
#pragma unroll
    for (int i = 0; i < 4; i++) {
      int idx = tid + i * 256;
      int m = idx >> 4, kk = idx & 15;
      float v = A[(size_t)(bm + m) * 512 + k0 + kk];
      As[kk][m] = fmaf(v, scale[k0 + kk], shift[k0 + kk]);
    }
#pragma unroll
    for (int i = 0; i < 4; i++) {
      int idx = tid + i * 256;
      int kk = idx >> 6, n = idx & 63;
      Bs[kk][n] = W[(size_t)(k0 + kk) * 512 + bn + n];
    }
    __syncthreads();
#pragma unroll
    for (int kk = 0; kk < 16; kk++) {
      float a4[4], b4[4];
      *(float4*)a4 = *(const float4*)&As[kk][ty * 4];
      *(float4*)b4 = *(const float4*)&Bs[kk][tx * 4];
#pragma unroll
      for (int i = 0; i < 4; i++)
#pragma unroll
        for (int j = 0; j < 4; j++) acc[i][j] = fmaf(a4[i], b4[j], acc[i][j]);
    }
    __syncthreads();
  }

  float bv[4];
  *(float4*)bv = *(const float4*)&bias[bn + tx * 4];
#pragma unroll
  for (int i = 0; i < 4; i++) {
#pragma unroll
    for (int j = 0; j < 4; j++) {
      float v = acc[i][j] + bv[j];
      if (do_gelu) v = gelu_tanh(v);
      acc[i][j] = v;
    }
    *(float4*)&C[(size_t)(bm + ty * 4 + i) * 512 + bn + tx * 4] = *(float4*)&acc[i][0];
  }

  if (accS != nullptr) {
    if (tid < 64) { colS[tid] = 0.f; colQ[tid] = 0.f; }
    __syncthreads();
#pragma unroll
    for (int j = 0; j < 4; j++) {
      float s = 0.f, q = 0.f;
#pragma unroll
      for (int i = 0; i < 4; i++) { s += acc[i][j]; q += acc[i][j] * acc[i][j]; }
      atomicAdd(&colS[tx * 4 + j], s);
      atomicAdd(&colQ[tx * 4 + j], q);
    }
    __syncthreads();
    if (tid < 64) {
      atomicAdd(&accS[bn + tid], colS[tid]);
      atomicAdd(&accQ[bn + tid], colQ[tid]);
    }
  }
}

// ---------------------------------------------------------------------------
// Final row L2 normalization, in place over d_out (32768 rows x 512)
// ---------------------------------------------------------------------------
__global__ __launch_bounds__(256) void l2norm_kernel(float* __restrict__ out) {
  const int wave = blockIdx.x * 4 + (threadIdx.x >> 6);
  const int lane = threadIdx.x & 63;
  float* p = out + (size_t)wave * DDIM + lane * 4;
  float v[8];
  ld8(p, v);
  float ss = 0.f;
#pragma unroll
  for (int j = 0; j < 8; j++) ss += v[j] * v[j];
  ss = wave_sum(ss);
  const float inv = 1.0f / sqrtf(ss);
#pragma unroll
  for (int j = 0; j < 8; j++) v[j] *= inv;
  st8(p, v);
}

extern "C" void kernel_launch(void* const* d_in, const int* in_sizes, int n_in,
                              void* d_out, int out_size, void* d_ws, size_t ws_size,
                              hipStream_t stream) {
  const float* img     = (const float*)d_in[0];
  const float* txt     = (const float*)d_in[1];
  const float* wg_w1   = (const float*)d_in[2];
  const float* wg_b1   = (const float*)d_in[3];
  const float* wg_w2   = (const float*)d_in[4];
  const float* wg_b2   = (const float*)d_in[5];
  const float* conv_w  = (const float*)d_in[6];
  const float* conv_b  = (const float*)d_in[7];
  const float* mg_bn_g = (const float*)d_in[8];
  const float* mg_bn_b = (const float*)d_in[9];
  const float* mg_w    = (const float*)d_in[10];
  const float* mg_b    = (const float*)d_in[11];
  const float* ph_bn1_g= (const float*)d_in[12];
  const float* ph_bn1_b= (const float*)d_in[13];
  const float* ph_w1   = (const float*)d_in[14];
  const float* ph_b1   = (const float*)d_in[15];
  const float* ph_bn2_g= (const float*)d_in[16];
  const float* ph_bn2_b= (const float*)d_in[17];
  const float* ph_w2   = (const float*)d_in[18];
  const float* ph_b2   = (const float*)d_in[19];
  float* out = (float*)d_out;

  const size_t BD = (size_t)NROWS * DDIM;
  float* ws    = (float*)d_ws;
  float* x     = ws;             // reused as t1_img after GEMM1
  float* fused = ws + BD;
  float* t1f   = ws + 2 * BD;
  float* acc   = ws + 3 * BD;    // 10*512 stats accumulators
  float* aff   = acc + 10 * 512; // 10*512 affine params

  float* accXs = acc + 0 * 512, *accXq = acc + 1 * 512;
  float* accIs = acc + 2 * 512, *accIq = acc + 3 * 512;
  float* accFs = acc + 4 * 512, *accFq = acc + 5 * 512;
  float* accT1s= acc + 6 * 512, *accT1q= acc + 7 * 512;
  float* accT2s= acc + 8 * 512, *accT2q= acc + 9 * 512;
  float* a0s = aff + 0 * 512, *a0h = aff + 1 * 512;
  float* a1s = aff + 2 * 512, *a1h = aff + 3 * 512;
  float* a2s = aff + 4 * 512, *a2h = aff + 5 * 512;
  float* a3s = aff + 6 * 512, *a3h = aff + 7 * 512;
  float* a4s = aff + 8 * 512, *a4h = aff + 9 * 512;

  hipMemsetAsync(acc, 0, 10 * 512 * sizeof(float), stream);

  prep_kernel<<<512, 256, 0, stream>>>(img, txt, wg_w1, wg_b1, wg_w2, wg_b2,
                                       conv_w, conv_b, x, accXs, accXq, accIs, accIq);
  const float invM = 1.0f / (float)NROWS;
  finalize_kernel<<<1, 512, 0, stream>>>(accXs, accXq, mg_bn_g, mg_bn_b, a0s, a0h, invM);
  finalize_kernel<<<1, 512, 0, stream>>>(accIs, accIq, ph_bn1_g, ph_bn1_b, a1s, a1h, invM);

  dim3 ggrid(NROWS / 64, DDIM / 64);
  // fused = gelu(BN(x) @ mg_w + mg_b), + stats of fused
  gemm_kernel<<<ggrid, 256, 0, stream>>>(x, mg_w, mg_b, a0s, a0h, fused, 1, accFs, accFq);
  finalize_kernel<<<1, 512, 0, stream>>>(accFs, accFq, ph_bn1_g, ph_bn1_b, a2s, a2h, invM);

  // t1_img = gelu(BN(img) @ ph_w1 + ph_b1)  (written into x buffer)
  gemm_kernel<<<ggrid, 256, 0, stream>>>(img, ph_w1, ph_b1, a1s, a1h, x, 1, accT1s, accT1q);
  // t1_fused = gelu(BN(fused) @ ph_w1 + ph_b1)
  gemm_kernel<<<ggrid, 256, 0, stream>>>(fused, ph_w1, ph_b1, a2s, a2h, t1f, 1, accT2s, accT2q);

  finalize_kernel<<<1, 512, 0, stream>>>(accT1s, accT1q, ph_bn2_g, ph_bn2_b, a3s, a3h, invM);
  finalize_kernel<<<1, 512, 0, stream>>>(accT2s, accT2q, ph_bn2_g, ph_bn2_b, a4s, a4h, invM);

  // final projections (no activation), straight into d_out halves
  gemm_kernel<<<ggrid, 256, 0, stream>>>(x, ph_w2, ph_b2, a3s, a3h, out, 0, nullptr, nullptr);
  gemm_kernel<<<ggrid, 256, 0, stream>>>(t1f, ph_w2, ph_b2, a4s, a4h, out + BD, 0, nullptr, nullptr);

  // row-wise L2 normalize both outputs in place
  l2norm_kernel<<<(2 * NROWS) / 4, 256, 0, stream>>>(out);
}

// Round 4
// 518.931 us; speedup vs baseline: 2.0682x; 2.0682x over previous
//
#include <hip/hip_runtime.h>
#include <cmath>

// Problem constants
#define NROWS 16384
#define DDIM  512

typedef __attribute__((ext_vector_type(8))) short          bf16x8;
typedef __attribute__((ext_vector_type(4))) float          f32x4;
typedef __attribute__((ext_vector_type(8))) unsigned short u16x8;
typedef __attribute__((ext_vector_type(4))) unsigned short u16x4;

__device__ __forceinline__ unsigned short f2bf(float f) {
  unsigned u = __float_as_uint(f);
  u += 0x7fffu + ((u >> 16) & 1u);  // RNE; inputs finite
  return (unsigned short)(u >> 16);
}

__device__ __forceinline__ float gelu_tanh(float x) {
  float x3 = x * x * x;
  float t = tanhf(0.79788456080286535588f * (x + 0.044715f * x3));
  return 0.5f * x * (1.0f + t);
}

__device__ __forceinline__ void ld8(const float* p, float* v) {
  float4 a = *(const float4*)p;
  float4 b = *(const float4*)(p + 256);
  v[0] = a.x; v[1] = a.y; v[2] = a.z; v[3] = a.w;
  v[4] = b.x; v[5] = b.y; v[6] = b.z; v[7] = b.w;
}

__device__ __forceinline__ void st8(float* p, const float* v) {
  *(float4*)p = make_float4(v[0], v[1], v[2], v[3]);
  *(float4*)(p + 256) = make_float4(v[4], v[5], v[6], v[7]);
}

__device__ __forceinline__ float wave_sum(float v) {
#pragma unroll
  for (int m = 1; m < 64; m <<= 1) v += __shfl_xor(v, m, 64);
  return v;
}

// ---------------------------------------------------------------------------
// Kernel 1: per-row prep (gate numerics FROZEN from round 3 — do not touch).
// Only change: x written as bf16 (it is only consumed as a bf16 MFMA operand).
// Stats still accumulated from exact fp32 values.
// ---------------------------------------------------------------------------
__global__ __launch_bounds__(256) void prep_kernel(
    const float* __restrict__ img, const float* __restrict__ txt,
    const float* __restrict__ wg_w1, const float* __restrict__ wg_b1,
    const float* __restrict__ wg_w2, const float* __restrict__ wg_b2,
    const float* __restrict__ conv_w, const float* __restrict__ conv_b,
    unsigned short* __restrict__ xbf,
    float* __restrict__ accXs, float* __restrict__ accXq,
    float* __restrict__ accIs, float* __restrict__ accIq) {
  __shared__ float csX[512], cqX[512], csI[512], cqI[512];
  const int tid = threadIdx.x;
  for (int i = tid; i < 512; i += 256) {
    csX[i] = 0.f; cqX[i] = 0.f; csI[i] = 0.f; cqI[i] = 0.f;
  }
  __syncthreads();

  const int lane = tid & 63;
  const int gwave = blockIdx.x * 4 + (tid >> 6);  // 0..2047

  const float cb = conv_b[0];
  const double b2 = (double)wg_b2[0];
  double w1r[16], b1r[16], w2r[16];
#pragma unroll
  for (int i = 0; i < 16; i++) {
    w1r[i] = (double)wg_w1[i]; b1r[i] = (double)wg_b1[i]; w2r[i] = (double)wg_w2[i];
  }
  float cw[5];
#pragma unroll
  for (int k = 0; k < 5; k++) cw[k] = conv_w[k];

  float sX[8] = {0, 0, 0, 0, 0, 0, 0, 0}, qX[8] = {0, 0, 0, 0, 0, 0, 0, 0};
  float sI[8] = {0, 0, 0, 0, 0, 0, 0, 0}, qI[8] = {0, 0, 0, 0, 0, 0, 0, 0};

  for (int it = 0; it < 8; it++) {
    const int r = gwave * 8 + it;
    const float* ip = img + (size_t)r * DDIM + lane * 4;
    float iv[8];
    ld8(ip, iv);
    double ss = 0.0;
#pragma unroll
    for (int j = 0; j < 8; j++) ss += (double)iv[j] * (double)iv[j];
#pragma unroll
    for (int m = 1; m < 64; m <<= 1) ss += __shfl_xor(ss, m, 64);
    const double dimg = fmax(sqrt(ss), 1e-12);

    float tv[5][8];
    double simv[5];
#pragma unroll
    for (int k = 0; k < 5; k++) {
      const float* tp = txt + ((size_t)r * 5 + k) * DDIM + lane * 4;
      ld8(tp, tv[k]);
      double s2 = 0.0, dp = 0.0;
#pragma unroll
      for (int j = 0; j < 8; j++) {
        s2 += (double)tv[k][j] * (double)tv[k][j];
        dp += (double)iv[j] * (double)tv[k][j];
      }
#pragma unroll
      for (int m = 1; m < 64; m <<= 1) {
        s2 += __shfl_xor(s2, m, 64);
        dp += __shfl_xor(dp, m, 64);
      }
      const double dt = fmax(sqrt(s2), 1e-12);
      simv[k] = dp / (dimg * dt);
    }

    // WeightGate logit in fp64 (true ordering), sigmoid emulating fp32 chain
    float wv[5];
#pragma unroll
    for (int k = 0; k < 5; k++) {
      double o = b2;
#pragma unroll
      for (int i = 0; i < 16; i++) {
        double h = simv[k] * w1r[i] + b1r[i];
        h = fmax(h, 0.0);
        o += h * w2r[i];
      }
      float o32 = (float)o;
      float e32 = (float)exp(-(double)o32);  // correctly-rounded f32 exp
      float a32 = 1.0f + e32;
      wv[k] = 1.0f / a32;
    }

    // stable descending rank -> coefficient
    float c[5];
#pragma unroll
    for (int k = 0; k < 5; k++) {
      int rk = 0;
#pragma unroll
      for (int j = 0; j < 5; j++)
        rk += (int)((wv[j] > wv[k]) || ((wv[j] == wv[k]) && (j < k)));
      c[k] = cw[rk] * wv[k];
    }

    float xv[8];
#pragma unroll
    for (int j = 0; j < 8; j++) {
      float v = cb;
#pragma unroll
      for (int k = 0; k < 5; k++) v = fmaf(c[k], tv[k][j], v);
      xv[j] = v;
    }
    {
      u16x4 lo, hi;
#pragma unroll
      for (int j = 0; j < 4; j++) { lo[j] = f2bf(xv[j]); hi[j] = f2bf(xv[4 + j]); }
      *(u16x4*)(xbf + (size_t)r * DDIM + lane * 4) = lo;
      *(u16x4*)(xbf + (size_t)r * DDIM + 256 + lane * 4) = hi;
    }

#pragma unroll
    for (int j = 0; j < 8; j++) {
      sX[j] += xv[j]; qX[j] += xv[j] * xv[j];
      sI[j] += iv[j]; qI[j] += iv[j] * iv[j];
    }
  }

  const int c0 = lane * 4, c1 = 256 + lane * 4;
#pragma unroll
  for (int j = 0; j < 4; j++) {
    atomicAdd(&csX[c0 + j], sX[j]);     atomicAdd(&cqX[c0 + j], qX[j]);
    atomicAdd(&csX[c1 + j], sX[4 + j]); atomicAdd(&cqX[c1 + j], qX[4 + j]);
    atomicAdd(&csI[c0 + j], sI[j]);     atomicAdd(&cqI[c0 + j], qI[j]);
    atomicAdd(&csI[c1 + j], sI[4 + j]); atomicAdd(&cqI[c1 + j], qI[4 + j]);
  }
  __syncthreads();
  for (int i = tid; i < 512; i += 256) {
    atomicAdd(&accXs[i], csX[i]); atomicAdd(&accXq[i], cqX[i]);
    atomicAdd(&accIs[i], csI[i]); atomicAdd(&accIq[i], cqI[i]);
  }
}

// ---------------------------------------------------------------------------
// fp32 -> bf16 bulk convert (for image_embedding)
// ---------------------------------------------------------------------------
__global__ __launch_bounds__(256) void cvt_kernel(const float* __restrict__ src,
                                                  unsigned short* __restrict__ dst) {
  size_t i = ((size_t)blockIdx.x * 256 + threadIdx.x) * 8;
  float4 a = *(const float4*)(src + i);
  float4 b = *(const float4*)(src + i + 4);
  u16x8 o;
  o[0] = f2bf(a.x); o[1] = f2bf(a.y); o[2] = f2bf(a.z); o[3] = f2bf(a.w);
  o[4] = f2bf(b.x); o[5] = f2bf(b.y); o[6] = f2bf(b.z); o[7] = f2bf(b.w);
  *(u16x8*)(dst + i) = o;
}

// ---------------------------------------------------------------------------
// finalize: BN stats -> affine (scale = g*rstd, shift = b - mean*scale)
// ---------------------------------------------------------------------------
__global__ void finalize_kernel(const float* __restrict__ s, const float* __restrict__ q,
                                const float* __restrict__ g, const float* __restrict__ b,
                                float* __restrict__ scale, float* __restrict__ shift,
                                float invM) {
  int j = threadIdx.x;
  if (j >= 512) return;
  float m = s[j] * invM;
  float v = q[j] * invM - m * m;
  float r = 1.0f / sqrtf(v + 1e-5f);
  float sc = g[j] * r;
  scale[j] = sc;
  shift[j] = fmaf(-m, sc, b[j]);
}

// ---------------------------------------------------------------------------
// Weight prep: Wt[n][k] = bf16(scale[k] * W[k][n])  (transpose + fold BN scale)
//              addv[n] += sum_k shift[k] * W[k][n]  (exact fp32 shift term)
// grid (16,16), 32x32 tile per block.
// ---------------------------------------------------------------------------
__global__ __launch_bounds__(256) void wconv_kernel(
    const float* __restrict__ W, const float* __restrict__ scale,
    const float* __restrict__ shift, unsigned short* __restrict__ Wt,
    float* __restrict__ addv) {
  __shared__ float T[32][33];
  __shared__ float P[32];
  const int t = threadIdx.x;
  const int k0 = blockIdx.x * 32, n0 = blockIdx.y * 32;
  {
    int r = t >> 3, c = (t & 7) * 4;
    float4 v = *(const float4*)&W[(size_t)(k0 + r) * 512 + n0 + c];
    T[r][c] = v.x; T[r][c + 1] = v.y; T[r][c + 2] = v.z; T[r][c + 3] = v.w;
  }
  if (t < 32) P[t] = 0.f;
  __syncthreads();
  {
    int n = t >> 3, k = (t & 7) * 4;
    u16x4 o;
#pragma unroll
    for (int i = 0; i < 4; i++) o[i] = f2bf(T[k + i][n] * scale[k0 + k + i]);
    *(u16x4*)&Wt[(size_t)(n0 + n) * 512 + k0 + k] = o;
  }
  {
    int n = t & 31, rb = (t >> 5) * 4;
    float p = 0.f;
#pragma unroll
    for (int i = 0; i < 4; i++) p += shift[k0 + rb + i] * T[rb + i][n];
    atomicAdd(&P[n], p);
  }
  __syncthreads();
  if (t < 32) atomicAdd(&addv[n0 + t], P[t]);
}

// ---------------------------------------------------------------------------
// bf16 MFMA GEMM: C = act( A @ Wt^T + bias + addv ), A:[16384,512] bf16,
// Wt:[512,512] bf16 stored [n][k]. Tile 128x128, BK=32, 4 waves (2x2),
// 16x16x32 MFMA, 4x4 tiles/wave. LDS XOR-swizzle (kl ^= (row>>1)&3) makes
// ds_read_b128 frag loads conflict-free. Register-prefetched staging.
// Output: bf16 (Cb, feeds next GEMM) or fp32 (Cf, final). Optional col stats.
// ---------------------------------------------------------------------------
__global__ __launch_bounds__(256) void gemm_bf16(
    const unsigned short* __restrict__ A, const unsigned short* __restrict__ Wt,
    const float* __restrict__ bias, const float* __restrict__ addv,
    float* __restrict__ Cf, unsigned short* __restrict__ Cb, int do_gelu,
    float* __restrict__ accS, float* __restrict__ accQ) {
  __shared__ __align__(16) short As[128 * 32];
  __shared__ __align__(16) short Bs[128 * 32];
  __shared__ float colS[128], colQ[128];
  const int tid = threadIdx.x;
  const int ln = tid & 63;
  const int lq = ln >> 4, lr = ln & 15;
  const int wv = tid >> 6;
  const int wm = wv >> 1, wn = wv & 1;
  const int bm = blockIdx.x * 128, bn = blockIdx.y * 128;

  f32x4 acc[4][4];
#pragma unroll
  for (int i = 0; i < 4; i++)
#pragma unroll
    for (int j = 0; j < 4; j++) acc[i][j] = (f32x4){0.f, 0.f, 0.f, 0.f};

  // staging addresses: thread covers LDS 16B slots idx0, idx1 (512 slots/matrix)
  const int idx0 = tid, idx1 = 256 + tid;
  const int r0 = idx0 >> 2, k0g = (idx0 & 3) ^ ((r0 >> 1) & 3);
  const int r1 = idx1 >> 2, k1g = (idx1 & 3) ^ ((r1 >> 1) & 3);
  const unsigned short* ga0 = A + (size_t)(bm + r0) * 512 + k0g * 8;
  const unsigned short* ga1 = A + (size_t)(bm + r1) * 512 + k1g * 8;
  const unsigned short* gb0 = Wt + (size_t)(bn + r0) * 512 + k0g * 8;
  const unsigned short* gb1 = Wt + (size_t)(bn + r1) * 512 + k1g * 8;

  u16x8 va0 = *(const u16x8*)ga0, va1 = *(const u16x8*)ga1;
  u16x8 vb0 = *(const u16x8*)gb0, vb1 = *(const u16x8*)gb1;

  for (int kk = 0; kk < 512; kk += 32) {
    *(u16x8*)((char*)As + idx0 * 16) = va0;
    *(u16x8*)((char*)As + idx1 * 16) = va1;
    *(u16x8*)((char*)Bs + idx0 * 16) = vb0;
    *(u16x8*)((char*)Bs + idx1 * 16) = vb1;
    __syncthreads();
    if (kk + 32 < 512) {
      va0 = *(const u16x8*)(ga0 + kk + 32);
      va1 = *(const u16x8*)(ga1 + kk + 32);
      vb0 = *(const u16x8*)(gb0 + kk + 32);
      vb1 = *(const u16x8*)(gb1 + kk + 32);
    }
    bf16x8 af[4], bfr[4];
#pragma unroll
    for (int i = 0; i < 4; i++) {
      int r = wm * 64 + i * 16 + lr;
      af[i] = *(const bf16x8*)((const char*)As + r * 64 + ((lq ^ ((r >> 1) & 3)) << 4));
    }
#pragma unroll
    for (int j = 0; j < 4; j++) {
      int n = wn * 64 + j * 16 + lr;
      bfr[j] = *(const bf16x8*)((const char*)Bs + n * 64 + ((lq ^ ((n >> 1) & 3)) << 4));
    }
#pragma unroll
    for (int i = 0; i < 4; i++)
#pragma unroll
      for (int j = 0; j < 4; j++)
        acc[i][j] = __builtin_amdgcn_mfma_f32_16x16x32_bf16(af[i], bfr[j], acc[i][j], 0, 0, 0);
    __syncthreads();
  }

  // epilogue
  const bool do_stats = (accS != nullptr);
  if (do_stats) {
    if (tid < 128) { colS[tid] = 0.f; colQ[tid] = 0.f; }
    __syncthreads();
  }
  float badd[4];
  int cols[4];
#pragma unroll
  for (int j = 0; j < 4; j++) {
    int c = bn + wn * 64 + j * 16 + lr;
    cols[j] = c;
    badd[j] = bias[c] + addv[c];
  }
#pragma unroll
  for (int j = 0; j < 4; j++) {
    float s = 0.f, q = 0.f;
#pragma unroll
    for (int i = 0; i < 4; i++) {
      int rbase = bm + wm * 64 + i * 16 + lq * 4;
#pragma unroll
      for (int rg = 0; rg < 4; rg++) {
        float v = acc[i][j][rg] + badd[j];
        if (do_gelu) v = gelu_tanh(v);
        size_t off = (size_t)(rbase + rg) * 512 + cols[j];
        if (Cb) Cb[off] = f2bf(v);
        else Cf[off] = v;
        s += v; q += v * v;
      }
    }
    if (do_stats) {
      atomicAdd(&colS[wn * 64 + j * 16 + lr], s);
      atomicAdd(&colQ[wn * 64 + j * 16 + lr], q);
    }
  }
  if (do_stats) {
    __syncthreads();
    if (tid < 128) {
      atomicAdd(&accS[bn + tid], colS[tid]);
      atomicAdd(&accQ[bn + tid], colQ[tid]);
    }
  }
}

// ---------------------------------------------------------------------------
// Final row L2 normalization, in place over d_out (32768 rows x 512)
// ---------------------------------------------------------------------------
__global__ __launch_bounds__(256) void l2norm_kernel(float* __restrict__ out) {
  const int wave = blockIdx.x * 4 + (threadIdx.x >> 6);
  const int lane = threadIdx.x & 63;
  float* p = out + (size_t)wave * DDIM + lane * 4;
  float v[8];
  ld8(p, v);
  float ss = 0.f;
#pragma unroll
  for (int j = 0; j < 8; j++) ss += v[j] * v[j];
  ss = wave_sum(ss);
  const float inv = 1.0f / sqrtf(ss);
#pragma unroll
  for (int j = 0; j < 8; j++) v[j] *= inv;
  st8(p, v);
}

extern "C" void kernel_launch(void* const* d_in, const int* in_sizes, int n_in,
                              void* d_out, int out_size, void* d_ws, size_t ws_size,
                              hipStream_t stream) {
  const float* img     = (const float*)d_in[0];
  const float* txt     = (const float*)d_in[1];
  const float* wg_w1   = (const float*)d_in[2];
  const float* wg_b1   = (const float*)d_in[3];
  const float* wg_w2   = (const float*)d_in[4];
  const float* wg_b2   = (const float*)d_in[5];
  const float* conv_w  = (const float*)d_in[6];
  const float* conv_b  = (const float*)d_in[7];
  const float* mg_bn_g = (const float*)d_in[8];
  const float* mg_bn_b = (const float*)d_in[9];
  const float* mg_w    = (const float*)d_in[10];
  const float* mg_b    = (const float*)d_in[11];
  const float* ph_bn1_g= (const float*)d_in[12];
  const float* ph_bn1_b= (const float*)d_in[13];
  const float* ph_w1   = (const float*)d_in[14];
  const float* ph_b1   = (const float*)d_in[15];
  const float* ph_bn2_g= (const float*)d_in[16];
  const float* ph_bn2_b= (const float*)d_in[17];
  const float* ph_w2   = (const float*)d_in[18];
  const float* ph_b2   = (const float*)d_in[19];
  float* out = (float*)d_out;

  const size_t BD = (size_t)NROWS * DDIM;
  const size_t WSZ = 512 * 512;

  unsigned short* xbf   = (unsigned short*)d_ws;  // later reused as t1img bf16
  unsigned short* imgbf = xbf + BD;               // later reused as t1f bf16
  unsigned short* fusbf = imgbf + BD;
  unsigned short* Wt0   = fusbf + BD;
  unsigned short* Wt1   = Wt0 + WSZ;
  unsigned short* Wt2   = Wt1 + WSZ;
  unsigned short* Wt3   = Wt2 + WSZ;
  unsigned short* Wt4   = Wt3 + WSZ;
  float* acc  = (float*)(Wt4 + WSZ);   // 10*512 stats
  float* addv = acc + 10 * 512;        // 5*512 shift-row terms
  float* aff  = addv + 5 * 512;        // 10*512 affine params

  float* accXs = acc + 0 * 512, *accXq = acc + 1 * 512;
  float* accIs = acc + 2 * 512, *accIq = acc + 3 * 512;
  float* accFs = acc + 4 * 512, *accFq = acc + 5 * 512;
  float* accT1s= acc + 6 * 512, *accT1q= acc + 7 * 512;
  float* accT2s= acc + 8 * 512, *accT2q= acc + 9 * 512;
  float* add0 = addv + 0 * 512, *add1 = addv + 1 * 512, *add2 = addv + 2 * 512;
  float* add3 = addv + 3 * 512, *add4 = addv + 4 * 512;
  float* a0s = aff + 0 * 512, *a0h = aff + 1 * 512;
  float* a1s = aff + 2 * 512, *a1h = aff + 3 * 512;
  float* a2s = aff + 4 * 512, *a2h = aff + 5 * 512;
  float* a3s = aff + 6 * 512, *a3h = aff + 7 * 512;
  float* a4s = aff + 8 * 512, *a4h = aff + 9 * 512;

  hipMemsetAsync(acc, 0, 15 * 512 * sizeof(float), stream);

  cvt_kernel<<<4096, 256, 0, stream>>>(img, imgbf);
  prep_kernel<<<512, 256, 0, stream>>>(img, txt, wg_w1, wg_b1, wg_w2, wg_b2,
                                       conv_w, conv_b, xbf, accXs, accXq, accIs, accIq);
  const float invM = 1.0f / (float)NROWS;
  finalize_kernel<<<1, 512, 0, stream>>>(accXs, accXq, mg_bn_g, mg_bn_b, a0s, a0h, invM);
  finalize_kernel<<<1, 512, 0, stream>>>(accIs, accIq, ph_bn1_g, ph_bn1_b, a1s, a1h, invM);

  dim3 wgrid(16, 16);
  dim3 ggrid(NROWS / 128, DDIM / 128);

  wconv_kernel<<<wgrid, 256, 0, stream>>>(mg_w, a0s, a0h, Wt0, add0);
  // fused = gelu(BN0(x) @ mg_w + mg_b), stats(fused)
  gemm_bf16<<<ggrid, 256, 0, stream>>>(xbf, Wt0, mg_b, add0, nullptr, fusbf, 1, accFs, accFq);
  finalize_kernel<<<1, 512, 0, stream>>>(accFs, accFq, ph_bn1_g, ph_bn1_b, a2s, a2h, invM);

  wconv_kernel<<<wgrid, 256, 0, stream>>>(ph_w1, a1s, a1h, Wt1, add1);
  // t1_img = gelu(BN1(img) @ ph_w1 + ph_b1) -> reuse xbf buffer
  gemm_bf16<<<ggrid, 256, 0, stream>>>(imgbf, Wt1, ph_b1, add1, nullptr, xbf, 1, accT1s, accT1q);

  wconv_kernel<<<wgrid, 256, 0, stream>>>(ph_w1, a2s, a2h, Wt2, add2);
  // t1_fused = gelu(BN2(fused) @ ph_w1 + ph_b1) -> reuse imgbf buffer
  gemm_bf16<<<ggrid, 256, 0, stream>>>(fusbf, Wt2, ph_b1, add2, nullptr, imgbf, 1, accT2s, accT2q);

  finalize_kernel<<<1, 512, 0, stream>>>(accT1s, accT1q, ph_bn2_g, ph_bn2_b, a3s, a3h, invM);
  finalize_kernel<<<1, 512, 0, stream>>>(accT2s, accT2q, ph_bn2_g, ph_bn2_b, a4s, a4h, invM);

  wconv_kernel<<<wgrid, 256, 0, stream>>>(ph_w2, a3s, a3h, Wt3, add3);
  wconv_kernel<<<wgrid, 256, 0, stream>>>(ph_w2, a4s, a4h, Wt4, add4);

  // final projections straight into d_out halves (fp32, no activation)
  gemm_bf16<<<ggrid, 256, 0, stream>>>(xbf, Wt3, ph_b2, add3, out, nullptr, 0, nullptr, nullptr);
  gemm_bf16<<<ggrid, 256, 0, stream>>>(imgbf, Wt4, ph_b2, add4, out + BD, nullptr, 0, nullptr, nullptr);

  // row-wise L2 normalize both outputs in place
  l2norm_kernel<<<(2 * NROWS) / 4, 256, 0, stream>>>(out);
}